// Round 2
// baseline (1203.653 us; speedup 1.0000x reference)
//
#include <hip/hip_runtime.h>

#define BATCH 8
#define C 1024
#define TIN 8192
#define T 2048
#define NTOT (BATCH * C * T)   // 16777216 elements per output tensor

// ---------------------------------------------------------------------------
// Kernel 1: tap[b,c,t] = mean(x[b,c,4t..4t+3])
// Each thread: one float4 load -> one float store. Fully coalesced.
// ---------------------------------------------------------------------------
__global__ __launch_bounds__(256) void pool_kernel(const float* __restrict__ x,
                                                   float* __restrict__ tap) {
    int i = blockIdx.x * blockDim.x + threadIdx.x;   // tap element index
    const float4 v = reinterpret_cast<const float4*>(x)[i];
    tap[i] = (v.x + v.y + v.z + v.w) * 0.25f;
}

// ---------------------------------------------------------------------------
// Kernel 2/3: Out[b,m,t] = sum_k W[m,k] * In[b,k,t] + bias[m]
// f32 tiled GEMM: BM=BN=128, BK=16, 256 threads, 8x8 register tile/thread.
// W tile stored transposed in LDS (As[k][m]); In tile (Bs[k][n]) is
// float4-contiguous both staging and reading.
// ---------------------------------------------------------------------------
#define BM 128
#define BN 128
#define BK 16

__global__ __launch_bounds__(256, 2) void gemm_bias(const float* __restrict__ W,
                                                    const float* __restrict__ bias,
                                                    const float* __restrict__ In,
                                                    float* __restrict__ Out) {
    __shared__ float As[BK][BM];   // 8 KiB
    __shared__ float Bs[BK][BN];   // 8 KiB

    const int b  = blockIdx.z;
    const int m0 = blockIdx.y * BM;
    const int n0 = blockIdx.x * BN;
    const int tid = threadIdx.x;
    const int tx = tid & 15;   // n direction, 16 threads
    const int ty = tid >> 4;   // m direction, 16 threads

    const float* Wp = W + (size_t)m0 * C;
    const float* Ip = In + (size_t)b * C * T + n0;

    float acc[8][8];
    #pragma unroll
    for (int i = 0; i < 8; ++i)
        #pragma unroll
        for (int j = 0; j < 8; ++j) acc[i][j] = 0.0f;

    for (int k0 = 0; k0 < C; k0 += BK) {
        // --- stage W tile (128 m-rows x 16 k) transposed into As[k][m] ---
        #pragma unroll
        for (int r = 0; r < 2; ++r) {
            int idx = tid + r * 256;       // float4 index 0..511
            int row = idx >> 2;            // m row 0..127
            int cg  = idx & 3;             // k group (4 floats)
            float4 w = *reinterpret_cast<const float4*>(&Wp[(size_t)row * C + k0 + cg * 4]);
            As[cg * 4 + 0][row] = w.x;
            As[cg * 4 + 1][row] = w.y;
            As[cg * 4 + 2][row] = w.z;
            As[cg * 4 + 3][row] = w.w;
        }
        // --- stage In tile (16 k x 128 n) into Bs[k][n] ---
        #pragma unroll
        for (int r = 0; r < 2; ++r) {
            int idx = tid + r * 256;       // float4 index 0..511
            int row = idx >> 5;            // k 0..15
            int cg  = idx & 31;            // n group
            *reinterpret_cast<float4*>(&Bs[row][cg * 4]) =
                *reinterpret_cast<const float4*>(&Ip[(size_t)(k0 + row) * T + cg * 4]);
        }
        __syncthreads();

        #pragma unroll
        for (int k = 0; k < BK; ++k) {
            float a[8], bv[8];
            *reinterpret_cast<float4*>(&a[0])  = *reinterpret_cast<float4*>(&As[k][ty * 8]);
            *reinterpret_cast<float4*>(&a[4])  = *reinterpret_cast<float4*>(&As[k][ty * 8 + 4]);
            *reinterpret_cast<float4*>(&bv[0]) = *reinterpret_cast<float4*>(&Bs[k][tx * 8]);
            *reinterpret_cast<float4*>(&bv[4]) = *reinterpret_cast<float4*>(&Bs[k][tx * 8 + 4]);
            #pragma unroll
            for (int i = 0; i < 8; ++i)
                #pragma unroll
                for (int j = 0; j < 8; ++j)
                    acc[i][j] += a[i] * bv[j];
        }
        __syncthreads();
    }

    // --- epilogue: add bias, store float4 ---
    float* Op = Out + (size_t)b * C * T + n0;
    #pragma unroll
    for (int i = 0; i < 8; ++i) {
        const int m = m0 + ty * 8 + i;
        const float bb = bias[m];
        #pragma unroll
        for (int j4 = 0; j4 < 2; ++j4) {
            float4 o;
            o.x = acc[i][j4 * 4 + 0] + bb;
            o.y = acc[i][j4 * 4 + 1] + bb;
            o.z = acc[i][j4 * 4 + 2] + bb;
            o.w = acc[i][j4 * 4 + 3] + bb;
            *reinterpret_cast<float4*>(&Op[(size_t)m * T + tx * 8 + j4 * 4]) = o;
        }
    }
}

// ---------------------------------------------------------------------------
// Kernel 4: ret[b,c,4q + {0..3}] = mean(ff2[b,c, max(0,s-15) .. s]), s = 4q
// One block per (b,c) row; row cached in LDS.
// ---------------------------------------------------------------------------
__global__ __launch_bounds__(512) void window_avg(const float* __restrict__ ff2,
                                                  float* __restrict__ ret) {
    __shared__ float row[T];
    const size_t bc = blockIdx.x;
    const float* src = ff2 + bc * T;
    float* dst = ret + bc * T;

    for (int i = threadIdx.x; i < T; i += 512) row[i] = src[i];
    __syncthreads();

    const int s = threadIdx.x * 4;          // 0,4,...,2044
    const int L = min(s + 1, 16);
    float sum = 0.0f;
    #pragma unroll 1
    for (int j = s - L + 1; j <= s; ++j) sum += row[j];
    const float avg = sum / (float)L;
    float4 o = {avg, avg, avg, avg};
    *reinterpret_cast<float4*>(&dst[s]) = o;
}

// ---------------------------------------------------------------------------
extern "C" void kernel_launch(void* const* d_in, const int* in_sizes, int n_in,
                              void* d_out, int out_size, void* d_ws, size_t ws_size,
                              hipStream_t stream) {
    const float* x  = (const float*)d_in[0];
    const float* W1 = (const float*)d_in[1];
    const float* b1 = (const float*)d_in[2];
    const float* W2 = (const float*)d_in[3];
    const float* b2 = (const float*)d_in[4];

    float* out = (float*)d_out;
    float* ret = out;                 // (B,C,T)
    float* tap = out + (size_t)NTOT;  // (B,C,T)
    float* ff1 = out + 2 * (size_t)NTOT;
    float* ff2 = out + 3 * (size_t)NTOT;

    // 1) pooling: 16.7M outputs
    pool_kernel<<<NTOT / 256, 256, 0, stream>>>(x, tap);

    // 2) ff1 = W1 @ tap + b1 ; 3) ff2 = W2 @ ff1 + b2
    dim3 grid(T / BN, C / BM, BATCH);   // (16, 8, 8) = 1024 blocks
    gemm_bias<<<grid, 256, 0, stream>>>(W1, b1, tap, ff1);
    gemm_bias<<<grid, 256, 0, stream>>>(W2, b2, ff1, ff2);

    // 4) windowed average + step-4 gather
    window_avg<<<BATCH * C, 512, 0, stream>>>(ff2, ret);
}

// Round 6
// 559.823 us; speedup vs baseline: 2.1501x; 2.1501x over previous
//
#include <hip/hip_runtime.h>

#define BATCH 8
#define C 1024
#define TIN 8192
#define T 2048
#define NTOT (BATCH * C * T)   // 16777216 elements per tensor

typedef __attribute__((ext_vector_type(8))) short short8;   // 8 bf16 = 4 VGPR
typedef __attribute__((ext_vector_type(4))) float f32x4;

__device__ __forceinline__ unsigned short f2bf(float f) {
    unsigned int u = __builtin_bit_cast(unsigned int, f);
    u += 0x7fff + ((u >> 16) & 1);           // round-to-nearest-even
    return (unsigned short)(u >> 16);
}

__device__ __forceinline__ void gload_lds16(const void* g, void* l) {
    __builtin_amdgcn_global_load_lds(
        (const __attribute__((address_space(1))) unsigned int*)g,
        (__attribute__((address_space(3))) unsigned int*)l, 16, 0, 0);
}

// ---------------------------------------------------------------------------
// Kernel 1a: tap f32 [b][c][t] (=mean of 4) AND tapT bf16 [b][t][c] (ws)
// ---------------------------------------------------------------------------
__global__ __launch_bounds__(256) void pool_dual(const float* __restrict__ x,
                                                 float* __restrict__ tap,
                                                 unsigned short* __restrict__ tapT) {
    __shared__ unsigned short trans[64][68];       // +4 pad
    const int b   = blockIdx.y;
    const int c0  = (blockIdx.x >> 5) * 64;        // 16 c-tiles
    const int t0  = (blockIdx.x & 31) * 64;        // 32 t-tiles
    const int tid = threadIdx.x;

    #pragma unroll
    for (int i = 0; i < 16; ++i) {
        const int idx = tid + i * 256;             // 0..4095
        const int dc = idx >> 6, dt = idx & 63;
        const float4 v = *reinterpret_cast<const float4*>(
            &x[((size_t)b * C + c0 + dc) * TIN + 4 * (t0 + dt)]);
        const float m = (v.x + v.y + v.z + v.w) * 0.25f;
        tap[((size_t)b * C + c0 + dc) * T + t0 + dt] = m;
        trans[dt][dc] = f2bf(m);
    }
    __syncthreads();

    #pragma unroll
    for (int it = 0; it < 4; ++it) {
        const int chunk = tid + it * 256;          // 0..1023 ushort4 chunks
        const int dt = chunk >> 4, cg = chunk & 15;
        const ushort4 o = *reinterpret_cast<const ushort4*>(&trans[dt][cg * 4]);
        *reinterpret_cast<ushort4*>(
            &tapT[((size_t)b * T + t0 + dt) * C + c0 + cg * 4]) = o;
    }
}

// ---------------------------------------------------------------------------
// Kernel 1b (fallback): tap only
// ---------------------------------------------------------------------------
__global__ __launch_bounds__(256) void pool_kernel(const float* __restrict__ x,
                                                   float* __restrict__ tap) {
    int i = blockIdx.x * blockDim.x + threadIdx.x;
    const float4 v = reinterpret_cast<const float4*>(x)[i];
    tap[i] = (v.x + v.y + v.z + v.w) * 0.25f;
}

// ---------------------------------------------------------------------------
// Kernel 2: f32 -> bf16 convert (W1/W2, layout [m][k] kept)
// ---------------------------------------------------------------------------
__global__ __launch_bounds__(256) void convert_bf16(const float* __restrict__ src,
                                                    unsigned short* __restrict__ dst) {
    const int i = blockIdx.x * 256 + threadIdx.x;
    const float4 v = reinterpret_cast<const float4*>(src)[i];
    ushort4 o;
    o.x = f2bf(v.x); o.y = f2bf(v.y); o.z = f2bf(v.z); o.w = f2bf(v.w);
    reinterpret_cast<ushort4*>(dst)[i] = o;
}

// ---------------------------------------------------------------------------
// Kernel 3: bf16 MFMA GEMM (m97 structure).
//   Out[b][m][t] = sum_k A[m][k] * BT[b][t][k] + bias[m]     (f32 store)
//   if DUAL: OutT[b][t][m] = bf16(Out)                        (ws, for GEMM2)
// 128x128 tile, BK=32, 256 thr = 4 waves (2x2), 4x4 16x16x32 frags/wave.
// ---------------------------------------------------------------------------
template <int DUAL>
__global__ __launch_bounds__(256) void gemm_mfma(const unsigned short* __restrict__ Ab,
                                                 const float* __restrict__ bias,
                                                 const unsigned short* __restrict__ BTb,
                                                 float* __restrict__ Out,
                                                 unsigned short* __restrict__ OutT) {
    __shared__ unsigned short As[128 * 32];   // 8 KiB, [m][k] linear
    __shared__ unsigned short Bs[128 * 32];   // 8 KiB, [n][k] linear

    const int b  = blockIdx.z;
    const int m0 = blockIdx.y * 128;
    const int n0 = blockIdx.x * 128;
    const int tid  = threadIdx.x;
    const int lane = tid & 63;
    const int wave = tid >> 6;
    const int wm = wave >> 1, wn = wave & 1;   // 2x2 wave grid, 64x64 each

    const unsigned short* Abase = Ab + (size_t)m0 * C;
    const unsigned short* Bbase = BTb + ((size_t)b * T + n0) * C;

    f32x4 acc[4][4];
    #pragma unroll
    for (int i = 0; i < 4; ++i)
        #pragma unroll
        for (int j = 0; j < 4; ++j) acc[i][j] = (f32x4)0.0f;

    const int srow = (lane >> 2);              // 0..15 within chunk
    const int skof = (lane & 3) * 8;           // k offset of this lane's 16B

    for (int k0 = 0; k0 < C; k0 += 32) {
        #pragma unroll
        for (int r = 0; r < 2; ++r) {
            const int chunk = wave + r * 4;            // 0..7, 1 KiB each
            const int row = chunk * 16 + srow;
            gload_lds16(Abase + (size_t)row * C + k0 + skof,
                        (char*)As + chunk * 1024);
            gload_lds16(Bbase + (size_t)row * C + k0 + skof,
                        (char*)Bs + chunk * 1024);
        }
        __syncthreads();

        short8 a[4], bf[4];
        #pragma unroll
        for (int mi = 0; mi < 4; ++mi)
            a[mi] = *reinterpret_cast<const short8*>(
                &As[(wm * 64 + mi * 16 + (lane & 15)) * 32 + (lane >> 4) * 8]);
        #pragma unroll
        for (int ni = 0; ni < 4; ++ni)
            bf[ni] = *reinterpret_cast<const short8*>(
                &Bs[(wn * 64 + ni * 16 + (lane & 15)) * 32 + (lane >> 4) * 8]);

        #pragma unroll
        for (int mi = 0; mi < 4; ++mi)
            #pragma unroll
            for (int ni = 0; ni < 4; ++ni)
                acc[mi][ni] = __builtin_amdgcn_mfma_f32_16x16x32_bf16(
                    a[mi], bf[ni], acc[mi][ni], 0, 0, 0);
        __syncthreads();
    }

    // epilogue: C/D layout col=lane&15 (t), row=(lane>>4)*4+reg (m)
    float bv[4][4];
    #pragma unroll
    for (int mi = 0; mi < 4; ++mi)
        #pragma unroll
        for (int r = 0; r < 4; ++r)
            bv[mi][r] = bias[m0 + wm * 64 + mi * 16 + (lane >> 4) * 4 + r];

    #pragma unroll
    for (int mi = 0; mi < 4; ++mi) {
        const int mrow0 = m0 + wm * 64 + mi * 16 + (lane >> 4) * 4;
        #pragma unroll
        for (int ni = 0; ni < 4; ++ni) {
            const int t = n0 + wn * 64 + ni * 16 + (lane & 15);
            float v0 = acc[mi][ni][0] + bv[mi][0];
            float v1 = acc[mi][ni][1] + bv[mi][1];
            float v2 = acc[mi][ni][2] + bv[mi][2];
            float v3 = acc[mi][ni][3] + bv[mi][3];
            float* op = &Out[((size_t)b * C + mrow0) * T + t];
            op[0 * T] = v0; op[1 * T] = v1; op[2 * T] = v2; op[3 * T] = v3;
            if (DUAL) {
                ushort4 o;
                o.x = f2bf(v0); o.y = f2bf(v1); o.z = f2bf(v2); o.w = f2bf(v3);
                *reinterpret_cast<ushort4*>(
                    &OutT[((size_t)b * T + t) * C + mrow0]) = o;
            }
        }
    }
}

// ---------------------------------------------------------------------------
// Fallback f32 GEMM (round-2 verified): Out = W @ In + bias
// ---------------------------------------------------------------------------
#define BM 128
#define BN 128
#define BK 16

__global__ __launch_bounds__(256, 2) void gemm_bias(const float* __restrict__ W,
                                                    const float* __restrict__ bias,
                                                    const float* __restrict__ In,
                                                    float* __restrict__ Out) {
    __shared__ float As[BK][BM];
    __shared__ float Bs[BK][BN];

    const int b  = blockIdx.z;
    const int m0 = blockIdx.y * BM;
    const int n0 = blockIdx.x * BN;
    const int tid = threadIdx.x;
    const int tx = tid & 15;
    const int ty = tid >> 4;

    const float* Wp = W + (size_t)m0 * C;
    const float* Ip = In + (size_t)b * C * T + n0;

    float acc[8][8];
    #pragma unroll
    for (int i = 0; i < 8; ++i)
        #pragma unroll
        for (int j = 0; j < 8; ++j) acc[i][j] = 0.0f;

    for (int k0 = 0; k0 < C; k0 += BK) {
        #pragma unroll
        for (int r = 0; r < 2; ++r) {
            int idx = tid + r * 256;
            int row = idx >> 2;
            int cg  = idx & 3;
            float4 w = *reinterpret_cast<const float4*>(&Wp[(size_t)row * C + k0 + cg * 4]);
            As[cg * 4 + 0][row] = w.x;
            As[cg * 4 + 1][row] = w.y;
            As[cg * 4 + 2][row] = w.z;
            As[cg * 4 + 3][row] = w.w;
        }
        #pragma unroll
        for (int r = 0; r < 2; ++r) {
            int idx = tid + r * 256;
            int row = idx >> 5;
            int cg  = idx & 31;
            *reinterpret_cast<float4*>(&Bs[row][cg * 4]) =
                *reinterpret_cast<const float4*>(&Ip[(size_t)(k0 + row) * T + cg * 4]);
        }
        __syncthreads();

        #pragma unroll
        for (int k = 0; k < BK; ++k) {
            float a[8], bv[8];
            *reinterpret_cast<float4*>(&a[0])  = *reinterpret_cast<float4*>(&As[k][ty * 8]);
            *reinterpret_cast<float4*>(&a[4])  = *reinterpret_cast<float4*>(&As[k][ty * 8 + 4]);
            *reinterpret_cast<float4*>(&bv[0]) = *reinterpret_cast<float4*>(&Bs[k][tx * 8]);
            *reinterpret_cast<float4*>(&bv[4]) = *reinterpret_cast<float4*>(&Bs[k][tx * 8 + 4]);
            #pragma unroll
            for (int i = 0; i < 8; ++i)
                #pragma unroll
                for (int j = 0; j < 8; ++j)
                    acc[i][j] += a[i] * bv[j];
        }
        __syncthreads();
    }

    float* Op = Out + (size_t)b * C * T + n0;
    #pragma unroll
    for (int i = 0; i < 8; ++i) {
        const int m = m0 + ty * 8 + i;
        const float bb = bias[m];
        #pragma unroll
        for (int j4 = 0; j4 < 2; ++j4) {
            float4 o;
            o.x = acc[i][j4 * 4 + 0] + bb;
            o.y = acc[i][j4 * 4 + 1] + bb;
            o.z = acc[i][j4 * 4 + 2] + bb;
            o.w = acc[i][j4 * 4 + 3] + bb;
            *reinterpret_cast<float4*>(&Op[(size_t)m * T + tx * 8 + j4 * 4]) = o;
        }
    }
}

// ---------------------------------------------------------------------------
// Kernel 4: ret[b,c,4q+{0..3}] = mean(ff2[b,c, max(0,s-15)..s]), s=4q
// ---------------------------------------------------------------------------
__global__ __launch_bounds__(512) void window_avg(const float* __restrict__ ff2,
                                                  float* __restrict__ ret) {
    __shared__ float row[T];
    const size_t bc = blockIdx.x;
    const float* src = ff2 + bc * T;
    float* dst = ret + bc * T;

    // 512 threads x 1 float4 = 2048 floats
    const float4 rv = reinterpret_cast<const float4*>(src)[threadIdx.x];
    *reinterpret_cast<float4*>(&row[threadIdx.x * 4]) = rv;
    __syncthreads();

    const int s = threadIdx.x * 4;
    const int L = min(s + 1, 16);
    float sum = 0.0f;
    #pragma unroll 1
    for (int j = s - L + 1; j <= s; ++j) sum += row[j];
    const float avg = sum / (float)L;
    float4 o = {avg, avg, avg, avg};
    *reinterpret_cast<float4*>(&dst[s]) = o;
}

// ---------------------------------------------------------------------------
extern "C" void kernel_launch(void* const* d_in, const int* in_sizes, int n_in,
                              void* d_out, int out_size, void* d_ws, size_t ws_size,
                              hipStream_t stream) {
    const float* x  = (const float*)d_in[0];
    const float* W1 = (const float*)d_in[1];
    const float* b1 = (const float*)d_in[2];
    const float* W2 = (const float*)d_in[3];
    const float* b2 = (const float*)d_in[4];

    float* out = (float*)d_out;
    float* ret = out;                        // (B,C,T) f32
    float* tap = out + (size_t)NTOT;
    float* ff1 = out + 2 * (size_t)NTOT;
    float* ff2 = out + 3 * (size_t)NTOT;

    // bf16 workspace need: tapT 32MB + ff1T 32MB + W1b 2MB + W2b 2MB
    const size_t need = (2 * (size_t)NTOT + 2 * (size_t)C * C) * sizeof(unsigned short);

    if (ws_size >= need) {
        unsigned short* tapT = (unsigned short*)d_ws;
        unsigned short* ff1T = tapT + (size_t)NTOT;
        unsigned short* W1b  = tapT + 2 * (size_t)NTOT;
        unsigned short* W2b  = W1b + (size_t)C * C;

        pool_dual<<<dim3(512, BATCH), 256, 0, stream>>>(x, tap, tapT);
        convert_bf16<<<C * C / 1024, 256, 0, stream>>>(W1, W1b);
        convert_bf16<<<C * C / 1024, 256, 0, stream>>>(W2, W2b);

        dim3 grid(T / 128, C / 128, BATCH);      // (16, 8, 8)
        gemm_mfma<1><<<grid, 256, 0, stream>>>(W1b, b1, tapT, ff1, ff1T);
        gemm_mfma<0><<<grid, 256, 0, stream>>>(W2b, b2, ff1T, ff2, nullptr);
    } else {
        // f32 fallback (round-2 verified path)
        pool_kernel<<<NTOT / 256, 256, 0, stream>>>(x, tap);
        dim3 grid(T / BN, C / BM, BATCH);
        gemm_bias<<<grid, 256, 0, stream>>>(W1, b1, tap, ff1);
        gemm_bias<<<grid, 256, 0, stream>>>(W2, b2, ff1, ff2);
    }

    window_avg<<<BATCH * C, 512, 0, stream>>>(ff2, ret);
}